// Round 4
// baseline (255.245 us; speedup 1.0000x reference)
//
#include <hip/hip_runtime.h>

#define CLASS_NUM 19
#define NBINS (CLASS_NUM * CLASS_NUM)   // 361
#define HW (512 * 512)                  // 262144
#define NPIX (8 * HW)                   // 2097152
#define NVEC (NPIX / 4)                 // 524288 pixel-quads
#define HWV (HW / 4)                    // 65536 float4 per channel-image
#define NBLK 1024                       // kernel-1 blocks

__device__ __forceinline__ float max3(float a, float b, float c) {
    return fmaxf(fmaxf(a, b), c);      // fuses to v_max3_f32
}

// Kernel 1: 1024 blocks x 512 threads, one pixel-quad per thread.
// Per-block LDS histogram -> plain coalesced store of 361 partials to ws.
__global__ __launch_bounds__(512, 4) void confusion_partial_kernel(
    const float4* __restrict__ in,   // [B, C, HWV] as float4
    const int4*  __restrict__ tgt,   // [B, HWV] as int4
    int* __restrict__ ws)            // [NBLK][NBINS] partials
{
    __shared__ int hist[NBINS];
    for (int i = threadIdx.x; i < NBINS; i += 512) hist[i] = 0;
    __syncthreads();

    const int g   = blockIdx.x * 512 + threadIdx.x;   // [0, NVEC)
    const int b   = g >> 16;                          // g / HWV
    const int hwv = g & (HWV - 1);                    // g % HWV
    const float4* p = in + (size_t)b * (CLASS_NUM * HWV) + hwv;

    const int4 t = tgt[g];            // issue target load first

    float a0[CLASS_NUM], a1[CLASS_NUM], a2[CLASS_NUM], a3[CLASS_NUM];
    #pragma unroll
    for (int c = 0; c < CLASS_NUM; ++c) {
        float4 v = p[(size_t)c * HWV];
        a0[c] = v.x; a1[c] = v.y; a2[c] = v.z; a3[c] = v.w;
    }

    #define ARGMAX(a, idx)                                                   \
        int idx;                                                             \
        {                                                                    \
            float m0 = max3(a[0],  a[1],  a[2]);                             \
            float m1 = max3(a[3],  a[4],  a[5]);                             \
            float m2 = max3(a[6],  a[7],  a[8]);                             \
            float m3 = max3(a[9],  a[10], a[11]);                            \
            float m4 = max3(a[12], a[13], a[14]);                            \
            float m5 = max3(a[15], a[16], a[17]);                            \
            float n0 = max3(m0, m1, m2);                                     \
            float n1 = max3(m3, m4, m5);                                     \
            float m  = max3(n0, n1, a[18]);                                  \
            idx = 18;                                                        \
            _Pragma("unroll")                                                \
            for (int c = 17; c >= 0; --c) idx = (a[c] == m) ? c : idx;       \
        }

    ARGMAX(a0, i0)
    ARGMAX(a1, i1)
    ARGMAX(a2, i2)
    ARGMAX(a3, i3)

    atomicAdd(&hist[t.x * CLASS_NUM + i0], 1);
    atomicAdd(&hist[t.y * CLASS_NUM + i1], 1);
    atomicAdd(&hist[t.z * CLASS_NUM + i2], 1);
    atomicAdd(&hist[t.w * CLASS_NUM + i3], 1);

    __syncthreads();
    // Plain coalesced store of this block's partial histogram (no atomics).
    int* dst = ws + (size_t)blockIdx.x * NBINS;
    for (int i = threadIdx.x; i < NBINS; i += 512) dst[i] = hist[i];
}

// Kernel 2: sum the 1024 partials per bin, plain-store to d_out
// (overwrites poison; no pre-zero needed). Layout ws[b][i] makes the
// per-iteration lane reads contiguous -> coalesced.
__global__ __launch_bounds__(256) void reduce_kernel(
    const int* __restrict__ ws, int* __restrict__ out)
{
    const int i = blockIdx.x * 256 + threadIdx.x;
    if (i >= NBINS) return;
    int s = 0;
    #pragma unroll 8
    for (int b = 0; b < NBLK; ++b) s += ws[(size_t)b * NBINS + i];
    out[i] = s;
}

extern "C" void kernel_launch(void* const* d_in, const int* in_sizes, int n_in,
                              void* d_out, int out_size, void* d_ws, size_t ws_size,
                              hipStream_t stream) {
    const float4* in  = (const float4*)d_in[0];
    const int4*   tgt = (const int4*)d_in[1];
    int* out = (int*)d_out;
    int* ws  = (int*)d_ws;   // needs NBLK*NBINS*4 = 1.48 MB

    confusion_partial_kernel<<<NBLK, 512, 0, stream>>>(in, tgt, ws);
    reduce_kernel<<<(NBINS + 255) / 256, 256, 0, stream>>>(ws, out);
}

// Round 5
// 217.506 us; speedup vs baseline: 1.1735x; 1.1735x over previous
//
#include <hip/hip_runtime.h>

#define CLASS_NUM 19
#define NBINS (CLASS_NUM * CLASS_NUM)   // 361
#define HW (512 * 512)                  // 262144
#define NPIX (8 * HW)                   // 2097152
#define NVEC (NPIX / 4)                 // 524288 pixel-quads
#define HWV (HW / 4)                    // 65536 float4 per channel-image
#define QPT 2                           // pixel-quads per thread
#define TPB 512                         // threads per block
#define TILE (TPB * QPT)                // 1024 quads per block
#define NBLK (NVEC / TILE)              // 512 blocks

typedef float f4 __attribute__((ext_vector_type(4)));

__global__ void zero_out_kernel(int* __restrict__ out) {
    int t = threadIdx.x;
    if (t < NBINS) out[t] = 0;
}

// 512 blocks x 512 threads; each thread handles 2 pixel-quads 512 apart so a
// block's per-channel footprint is 16 KB contiguous (better DRAM burst
// locality than 8 KB). Incremental argmax with strict > (ascending c)
// preserves jnp.argmax first-occurrence tie semantics.
__global__ __launch_bounds__(TPB, 4) void confusion_kernel(
    const f4*   __restrict__ in,   // [B, C, HWV]
    const int4* __restrict__ tgt,  // [B, HWV] as int4
    int* __restrict__ out)         // [361]
{
    __shared__ int hist[NBINS];
    for (int i = threadIdx.x; i < NBINS; i += TPB) hist[i] = 0;
    __syncthreads();

    const int g0 = blockIdx.x * TILE + threadIdx.x;   // quad 0
    const int g1 = g0 + TPB;                          // quad 1
    const int b  = g0 >> 16;                          // image idx (same for g1)
    const int h0 = g0 & (HWV - 1);
    const f4* p0 = in + (size_t)b * (CLASS_NUM * HWV) + h0;
    const f4* p1 = p0 + TPB;

    const int4 t0 = tgt[g0];
    const int4 t1 = tgt[g1];

    f4 best0 = __builtin_nontemporal_load(p0);
    f4 best1 = __builtin_nontemporal_load(p1);
    int i0x = 0, i0y = 0, i0z = 0, i0w = 0;
    int i1x = 0, i1y = 0, i1z = 0, i1w = 0;

    #pragma unroll
    for (int c = 1; c < CLASS_NUM; ++c) {
        f4 v0 = __builtin_nontemporal_load(p0 + (size_t)c * HWV);
        f4 v1 = __builtin_nontemporal_load(p1 + (size_t)c * HWV);
        i0x = (v0.x > best0.x) ? c : i0x;  best0.x = fmaxf(best0.x, v0.x);
        i0y = (v0.y > best0.y) ? c : i0y;  best0.y = fmaxf(best0.y, v0.y);
        i0z = (v0.z > best0.z) ? c : i0z;  best0.z = fmaxf(best0.z, v0.z);
        i0w = (v0.w > best0.w) ? c : i0w;  best0.w = fmaxf(best0.w, v0.w);
        i1x = (v1.x > best1.x) ? c : i1x;  best1.x = fmaxf(best1.x, v1.x);
        i1y = (v1.y > best1.y) ? c : i1y;  best1.y = fmaxf(best1.y, v1.y);
        i1z = (v1.z > best1.z) ? c : i1z;  best1.z = fmaxf(best1.z, v1.z);
        i1w = (v1.w > best1.w) ? c : i1w;  best1.w = fmaxf(best1.w, v1.w);
    }

    atomicAdd(&hist[t0.x * CLASS_NUM + i0x], 1);
    atomicAdd(&hist[t0.y * CLASS_NUM + i0y], 1);
    atomicAdd(&hist[t0.z * CLASS_NUM + i0z], 1);
    atomicAdd(&hist[t0.w * CLASS_NUM + i0w], 1);
    atomicAdd(&hist[t1.x * CLASS_NUM + i1x], 1);
    atomicAdd(&hist[t1.y * CLASS_NUM + i1y], 1);
    atomicAdd(&hist[t1.z * CLASS_NUM + i1z], 1);
    atomicAdd(&hist[t1.w * CLASS_NUM + i1w], 1);

    __syncthreads();
    for (int i = threadIdx.x; i < NBINS; i += TPB) {
        int h = hist[i];
        if (h) atomicAdd(&out[i], h);
    }
}

extern "C" void kernel_launch(void* const* d_in, const int* in_sizes, int n_in,
                              void* d_out, int out_size, void* d_ws, size_t ws_size,
                              hipStream_t stream) {
    const f4*   in  = (const f4*)d_in[0];
    const int4* tgt = (const int4*)d_in[1];
    int* out = (int*)d_out;

    // d_out is re-poisoned to 0xAA before every timed launch — zero it first.
    zero_out_kernel<<<1, 512, 0, stream>>>(out);

    confusion_kernel<<<NBLK, TPB, 0, stream>>>(in, tgt, out);
}

// Round 6
// 216.731 us; speedup vs baseline: 1.1777x; 1.0036x over previous
//
#include <hip/hip_runtime.h>

#define CLASS_NUM 19
#define NBINS (CLASS_NUM * CLASS_NUM)   // 361
#define HW (512 * 512)                  // 262144
#define NPIX (8 * HW)                   // 2097152
#define NVEC (NPIX / 4)                 // 524288 pixel-quads
#define HWV (HW / 4)                    // 65536 float4 per channel-image
#define QPT 4                           // pixel-quads per thread
#define TPB 512                         // threads per block
#define TILE (TPB * QPT)                // 2048 quads per block
#define NBLK (NVEC / TILE)              // 256 blocks

typedef float f4 __attribute__((ext_vector_type(4)));

__global__ void zero_out_kernel(int* __restrict__ out) {
    int t = threadIdx.x;
    if (t < NBINS) out[t] = 0;
}

// 256 blocks x 512 threads; each thread handles 4 pixel-quads TPB apart so a
// block's per-channel footprint is 32 KB contiguous (DRAM burst locality).
// Incremental argmax with strict > (ascending c) preserves jnp.argmax
// first-occurrence tie semantics.
__global__ __launch_bounds__(TPB, 2) void confusion_kernel(
    const f4*   __restrict__ in,   // [B, C, HWV]
    const int4* __restrict__ tgt,  // [B, HWV] as int4
    int* __restrict__ out)         // [361]
{
    __shared__ int hist[NBINS];
    for (int i = threadIdx.x; i < NBINS; i += TPB) hist[i] = 0;
    __syncthreads();

    const int g0 = blockIdx.x * TILE + threadIdx.x;   // quad 0; TILE divides HWV*? (2048 | 65536) yes
    const int b  = g0 >> 16;                          // image idx (same for all 4 quads)
    const int h0 = g0 & (HWV - 1);
    const f4* p  = in + (size_t)b * (CLASS_NUM * HWV) + h0;

    const int4 t0 = tgt[g0];
    const int4 t1 = tgt[g0 + TPB];
    const int4 t2 = tgt[g0 + 2 * TPB];
    const int4 t3 = tgt[g0 + 3 * TPB];

    f4 best0 = __builtin_nontemporal_load(p);
    f4 best1 = __builtin_nontemporal_load(p + TPB);
    f4 best2 = __builtin_nontemporal_load(p + 2 * TPB);
    f4 best3 = __builtin_nontemporal_load(p + 3 * TPB);
    int i0x = 0, i0y = 0, i0z = 0, i0w = 0;
    int i1x = 0, i1y = 0, i1z = 0, i1w = 0;
    int i2x = 0, i2y = 0, i2z = 0, i2w = 0;
    int i3x = 0, i3y = 0, i3z = 0, i3w = 0;

    #pragma unroll
    for (int c = 1; c < CLASS_NUM; ++c) {
        const f4* q = p + (size_t)c * HWV;
        f4 v0 = __builtin_nontemporal_load(q);
        f4 v1 = __builtin_nontemporal_load(q + TPB);
        f4 v2 = __builtin_nontemporal_load(q + 2 * TPB);
        f4 v3 = __builtin_nontemporal_load(q + 3 * TPB);
        i0x = (v0.x > best0.x) ? c : i0x;  best0.x = fmaxf(best0.x, v0.x);
        i0y = (v0.y > best0.y) ? c : i0y;  best0.y = fmaxf(best0.y, v0.y);
        i0z = (v0.z > best0.z) ? c : i0z;  best0.z = fmaxf(best0.z, v0.z);
        i0w = (v0.w > best0.w) ? c : i0w;  best0.w = fmaxf(best0.w, v0.w);
        i1x = (v1.x > best1.x) ? c : i1x;  best1.x = fmaxf(best1.x, v1.x);
        i1y = (v1.y > best1.y) ? c : i1y;  best1.y = fmaxf(best1.y, v1.y);
        i1z = (v1.z > best1.z) ? c : i1z;  best1.z = fmaxf(best1.z, v1.z);
        i1w = (v1.w > best1.w) ? c : i1w;  best1.w = fmaxf(best1.w, v1.w);
        i2x = (v2.x > best2.x) ? c : i2x;  best2.x = fmaxf(best2.x, v2.x);
        i2y = (v2.y > best2.y) ? c : i2y;  best2.y = fmaxf(best2.y, v2.y);
        i2z = (v2.z > best2.z) ? c : i2z;  best2.z = fmaxf(best2.z, v2.z);
        i2w = (v2.w > best2.w) ? c : i2w;  best2.w = fmaxf(best2.w, v2.w);
        i3x = (v3.x > best3.x) ? c : i3x;  best3.x = fmaxf(best3.x, v3.x);
        i3y = (v3.y > best3.y) ? c : i3y;  best3.y = fmaxf(best3.y, v3.y);
        i3z = (v3.z > best3.z) ? c : i3z;  best3.z = fmaxf(best3.z, v3.z);
        i3w = (v3.w > best3.w) ? c : i3w;  best3.w = fmaxf(best3.w, v3.w);
    }

    atomicAdd(&hist[t0.x * CLASS_NUM + i0x], 1);
    atomicAdd(&hist[t0.y * CLASS_NUM + i0y], 1);
    atomicAdd(&hist[t0.z * CLASS_NUM + i0z], 1);
    atomicAdd(&hist[t0.w * CLASS_NUM + i0w], 1);
    atomicAdd(&hist[t1.x * CLASS_NUM + i1x], 1);
    atomicAdd(&hist[t1.y * CLASS_NUM + i1y], 1);
    atomicAdd(&hist[t1.z * CLASS_NUM + i1z], 1);
    atomicAdd(&hist[t1.w * CLASS_NUM + i1w], 1);
    atomicAdd(&hist[t2.x * CLASS_NUM + i2x], 1);
    atomicAdd(&hist[t2.y * CLASS_NUM + i2y], 1);
    atomicAdd(&hist[t2.z * CLASS_NUM + i2z], 1);
    atomicAdd(&hist[t2.w * CLASS_NUM + i2w], 1);
    atomicAdd(&hist[t3.x * CLASS_NUM + i3x], 1);
    atomicAdd(&hist[t3.y * CLASS_NUM + i3y], 1);
    atomicAdd(&hist[t3.z * CLASS_NUM + i3z], 1);
    atomicAdd(&hist[t3.w * CLASS_NUM + i3w], 1);

    __syncthreads();
    for (int i = threadIdx.x; i < NBINS; i += TPB) {
        int h = hist[i];
        if (h) atomicAdd(&out[i], h);
    }
}

extern "C" void kernel_launch(void* const* d_in, const int* in_sizes, int n_in,
                              void* d_out, int out_size, void* d_ws, size_t ws_size,
                              hipStream_t stream) {
    const f4*   in  = (const f4*)d_in[0];
    const int4* tgt = (const int4*)d_in[1];
    int* out = (int*)d_out;

    // d_out is re-poisoned to 0xAA before every timed launch — zero it first.
    zero_out_kernel<<<1, 512, 0, stream>>>(out);

    confusion_kernel<<<NBLK, TPB, 0, stream>>>(in, tgt, out);
}

// Round 7
// 216.192 us; speedup vs baseline: 1.1806x; 1.0025x over previous
//
#include <hip/hip_runtime.h>

#define CLASS_NUM 19
#define NBINS (CLASS_NUM * CLASS_NUM)   // 361
#define HW (512 * 512)                  // 262144
#define NPIX (8 * HW)                   // 2097152
#define NVEC (NPIX / 4)                 // 524288 pixel-quads
#define HWV (HW / 4)                    // 65536 float4 per channel-image
#define QPT 4                           // pixel-quads per thread
#define TPB 512                         // threads per block
#define TILE (TPB * QPT)                // 2048 quads per block
#define NBLK (NVEC / TILE)              // 256 blocks

typedef float f4 __attribute__((ext_vector_type(4)));

// Kernel 1: 256 blocks x 512 threads; each thread handles 4 pixel-quads TPB
// apart (32 KB contiguous per-channel block footprint -> DRAM burst locality).
// Per-block LDS histogram, then plain stores of partials transposed:
// ws[bin * NBLK + block] so kernel 2 reads each bin's partials coalesced.
__global__ __launch_bounds__(TPB, 2) void confusion_partial_kernel(
    const f4*   __restrict__ in,   // [B, C, HWV]
    const int4* __restrict__ tgt,  // [B, HWV] as int4
    int* __restrict__ ws)          // [NBINS][NBLK]
{
    __shared__ int hist[NBINS];
    for (int i = threadIdx.x; i < NBINS; i += TPB) hist[i] = 0;
    __syncthreads();

    const int g0 = blockIdx.x * TILE + threadIdx.x;
    const int b  = g0 >> 16;                          // image idx (same for all 4 quads)
    const int h0 = g0 & (HWV - 1);
    const f4* p  = in + (size_t)b * (CLASS_NUM * HWV) + h0;

    const int4 t0 = tgt[g0];
    const int4 t1 = tgt[g0 + TPB];
    const int4 t2 = tgt[g0 + 2 * TPB];
    const int4 t3 = tgt[g0 + 3 * TPB];

    f4 best0 = __builtin_nontemporal_load(p);
    f4 best1 = __builtin_nontemporal_load(p + TPB);
    f4 best2 = __builtin_nontemporal_load(p + 2 * TPB);
    f4 best3 = __builtin_nontemporal_load(p + 3 * TPB);
    int i0x = 0, i0y = 0, i0z = 0, i0w = 0;
    int i1x = 0, i1y = 0, i1z = 0, i1w = 0;
    int i2x = 0, i2y = 0, i2z = 0, i2w = 0;
    int i3x = 0, i3y = 0, i3z = 0, i3w = 0;

    #pragma unroll
    for (int c = 1; c < CLASS_NUM; ++c) {
        const f4* q = p + (size_t)c * HWV;
        f4 v0 = __builtin_nontemporal_load(q);
        f4 v1 = __builtin_nontemporal_load(q + TPB);
        f4 v2 = __builtin_nontemporal_load(q + 2 * TPB);
        f4 v3 = __builtin_nontemporal_load(q + 3 * TPB);
        i0x = (v0.x > best0.x) ? c : i0x;  best0.x = fmaxf(best0.x, v0.x);
        i0y = (v0.y > best0.y) ? c : i0y;  best0.y = fmaxf(best0.y, v0.y);
        i0z = (v0.z > best0.z) ? c : i0z;  best0.z = fmaxf(best0.z, v0.z);
        i0w = (v0.w > best0.w) ? c : i0w;  best0.w = fmaxf(best0.w, v0.w);
        i1x = (v1.x > best1.x) ? c : i1x;  best1.x = fmaxf(best1.x, v1.x);
        i1y = (v1.y > best1.y) ? c : i1y;  best1.y = fmaxf(best1.y, v1.y);
        i1z = (v1.z > best1.z) ? c : i1z;  best1.z = fmaxf(best1.z, v1.z);
        i1w = (v1.w > best1.w) ? c : i1w;  best1.w = fmaxf(best1.w, v1.w);
        i2x = (v2.x > best2.x) ? c : i2x;  best2.x = fmaxf(best2.x, v2.x);
        i2y = (v2.y > best2.y) ? c : i2y;  best2.y = fmaxf(best2.y, v2.y);
        i2z = (v2.z > best2.z) ? c : i2z;  best2.z = fmaxf(best2.z, v2.z);
        i2w = (v2.w > best2.w) ? c : i2w;  best2.w = fmaxf(best2.w, v2.w);
        i3x = (v3.x > best3.x) ? c : i3x;  best3.x = fmaxf(best3.x, v3.x);
        i3y = (v3.y > best3.y) ? c : i3y;  best3.y = fmaxf(best3.y, v3.y);
        i3z = (v3.z > best3.z) ? c : i3z;  best3.z = fmaxf(best3.z, v3.z);
        i3w = (v3.w > best3.w) ? c : i3w;  best3.w = fmaxf(best3.w, v3.w);
    }

    atomicAdd(&hist[t0.x * CLASS_NUM + i0x], 1);
    atomicAdd(&hist[t0.y * CLASS_NUM + i0y], 1);
    atomicAdd(&hist[t0.z * CLASS_NUM + i0z], 1);
    atomicAdd(&hist[t0.w * CLASS_NUM + i0w], 1);
    atomicAdd(&hist[t1.x * CLASS_NUM + i1x], 1);
    atomicAdd(&hist[t1.y * CLASS_NUM + i1y], 1);
    atomicAdd(&hist[t1.z * CLASS_NUM + i1z], 1);
    atomicAdd(&hist[t1.w * CLASS_NUM + i1w], 1);
    atomicAdd(&hist[t2.x * CLASS_NUM + i2x], 1);
    atomicAdd(&hist[t2.y * CLASS_NUM + i2y], 1);
    atomicAdd(&hist[t2.z * CLASS_NUM + i2z], 1);
    atomicAdd(&hist[t2.w * CLASS_NUM + i2w], 1);
    atomicAdd(&hist[t3.x * CLASS_NUM + i3x], 1);
    atomicAdd(&hist[t3.y * CLASS_NUM + i3y], 1);
    atomicAdd(&hist[t3.z * CLASS_NUM + i3z], 1);
    atomicAdd(&hist[t3.w * CLASS_NUM + i3w], 1);

    __syncthreads();
    // Transposed plain store: bin-major so the reducer reads coalesced.
    for (int i = threadIdx.x; i < NBINS; i += TPB)
        ws[(size_t)i * NBLK + blockIdx.x] = hist[i];
}

// Kernel 2: one wave per bin. 256 partials = 64 coalesced int4 per block
// (L2-hot), butterfly shuffle reduce, lane 0 plain-stores (overwrites the
// 0xAA poison -> no zeroing kernel needed anywhere).
__global__ __launch_bounds__(64) void reduce_kernel(
    const int4* __restrict__ ws4,   // [NBINS][NBLK/4]
    int* __restrict__ out)          // [361]
{
    const int4 v = ws4[(size_t)blockIdx.x * (NBLK / 4) + threadIdx.x];
    int s = v.x + v.y + v.z + v.w;
    #pragma unroll
    for (int off = 32; off > 0; off >>= 1) s += __shfl_down(s, off, 64);
    if (threadIdx.x == 0) out[blockIdx.x] = s;
}

extern "C" void kernel_launch(void* const* d_in, const int* in_sizes, int n_in,
                              void* d_out, int out_size, void* d_ws, size_t ws_size,
                              hipStream_t stream) {
    const f4*   in  = (const f4*)d_in[0];
    const int4* tgt = (const int4*)d_in[1];
    int* out = (int*)d_out;
    int* ws  = (int*)d_ws;   // needs NBINS*NBLK*4 = 370 KB

    confusion_partial_kernel<<<NBLK, TPB, 0, stream>>>(in, tgt, ws);
    reduce_kernel<<<NBINS, 64, 0, stream>>>((const int4*)ws, out);
}